// Round 1
// baseline (543.634 us; speedup 1.0000x reference)
//
#include <hip/hip_runtime.h>
#include <stdint.h>
#include <stdio.h>

#define B_   2
#define T_   1024
#define C_   1024
#define H_   4096
#define ER_  8
#define ES_  2
#define NTOK (B_*T_)   // 2048

typedef __attribute__((ext_vector_type(4))) float  f32x4;
typedef __attribute__((ext_vector_type(8))) __bf16 bf16x8;

__device__ __forceinline__ unsigned short f2bf(float f) {
  unsigned u = __builtin_bit_cast(unsigned, f);
  u += 0x7FFFu + ((u >> 16) & 1u);          // RNE
  return (unsigned short)(u >> 16);
}

__device__ __forceinline__ void async_ld16(void* lds, const void* g) {
  __builtin_amdgcn_global_load_lds(
      (const __attribute__((address_space(1))) char*)(uintptr_t)g,
      (__attribute__((address_space(3))) char*)(uintptr_t)lds, 16, 0, 0);
}

__device__ __forceinline__ f32x4 mfma16(bf16x8 a, bf16x8 b, f32x4 c) {
  return __builtin_amdgcn_mfma_f32_16x16x32_bf16(a, b, c, 0, 0, 0);
}

// ---------------------------------------------------------------- init out = u
__global__ void k_init(const float* __restrict__ u, float* __restrict__ out) {
  size_t i = (size_t)blockIdx.x * 256 + threadIdx.x;
  reinterpret_cast<float4*>(out)[i] = reinterpret_cast<const float4*>(u)[i];
}

// -------------------------------------------- per-token norm scales + routing
__global__ void k_prep(const float* __restrict__ u, const float* __restrict__ gs,
                       const float* __restrict__ gr, const float* __restrict__ cent,
                       __bf16* __restrict__ xns, __bf16* __restrict__ xnr,
                       int* __restrict__ tki, float* __restrict__ tkg)
{
  const int t = blockIdx.x, tid = threadIdx.x;
  float4 v = reinterpret_cast<const float4*>(u + (size_t)t * C_)[tid];
  float ss = v.x*v.x + v.y*v.y + v.z*v.z + v.w*v.w;
  const int c0 = tid * 4;
  float sc[ER_];
  #pragma unroll
  for (int e = 0; e < ER_; ++e) {
    sc[e] = v.x * cent[(c0+0)*ER_ + e] + v.y * cent[(c0+1)*ER_ + e]
          + v.z * cent[(c0+2)*ER_ + e] + v.w * cent[(c0+3)*ER_ + e];
  }
  #pragma unroll
  for (int o = 32; o > 0; o >>= 1) {
    ss += __shfl_down(ss, o);
    #pragma unroll
    for (int e = 0; e < ER_; ++e) sc[e] += __shfl_down(sc[e], o);
  }
  __shared__ float red[4][ER_ + 1];
  __shared__ float sbc;
  const int w = tid >> 6;
  if ((tid & 63) == 0) {
    red[w][0] = ss;
    #pragma unroll
    for (int e = 0; e < ER_; ++e) red[w][1 + e] = sc[e];
  }
  __syncthreads();
  if (tid == 0) {
    float S = red[0][0] + red[1][0] + red[2][0] + red[3][0];
    sbc = rsqrtf(S * (1.0f / C_) + 1.1920929e-07f);
    float p[ER_]; float psum = 0.f;
    #pragma unroll
    for (int e = 0; e < ER_; ++e) {
      float d = red[0][1+e] + red[1][1+e] + red[2][1+e] + red[3][1+e];
      p[e] = 1.f / (1.f + expf(-d));
      psum += p[e];
    }
    int i0 = 0;
    for (int e = 1; e < ER_; ++e) if (p[e] > p[i0]) i0 = e;
    int i1 = -1;
    for (int e = 0; e < ER_; ++e) { if (e == i0) continue; if (i1 < 0 || p[e] > p[i1]) i1 = e; }
    tki[t*2+0] = i0;  tki[t*2+1] = i1;
    tkg[t*2+0] = p[i0] / psum;  tkg[t*2+1] = p[i1] / psum;
  }
  __syncthreads();
  const float s = sbc;
  ushort4 os, orr;
  os.x  = f2bf(v.x * s * gs[c0+0]); os.y  = f2bf(v.y * s * gs[c0+1]);
  os.z  = f2bf(v.z * s * gs[c0+2]); os.w  = f2bf(v.w * s * gs[c0+3]);
  orr.x = f2bf(v.x * s * gr[c0+0]); orr.y = f2bf(v.y * s * gr[c0+1]);
  orr.z = f2bf(v.z * s * gr[c0+2]); orr.w = f2bf(v.w * s * gr[c0+3]);
  reinterpret_cast<ushort4*>(xns)[(size_t)t * (C_/4) + tid] = os;
  reinterpret_cast<ushort4*>(xnr)[(size_t)t * (C_/4) + tid] = orr;
}

// -------------------------------------------------- expert token-list builder
__global__ void k_build(const int* __restrict__ tki, const float* __restrict__ tkg,
                        int* __restrict__ listTok, float* __restrict__ listGate,
                        int* __restrict__ offs, int* __restrict__ cnts)
{
  __shared__ int cnt[ER_], cur[ER_], off[ER_];
  const int tid = threadIdx.x;
  if (tid < ER_) cnt[tid] = 0;
  __syncthreads();
  for (int i = tid; i < NTOK*2; i += 256) atomicAdd(&cnt[tki[i]], 1);
  __syncthreads();
  if (tid == 0) {
    int a = 0;
    for (int e = 0; e < ER_; ++e) { off[e] = a; cur[e] = a; a += cnt[e]; }
  }
  __syncthreads();
  for (int i = tid; i < NTOK*2; i += 256) {
    int e = tki[i];
    int p = atomicAdd(&cur[e], 1);
    listTok[p]  = i >> 1;
    listGate[p] = tkg[i];
  }
  if (tid < ER_) { offs[tid] = off[tid]; cnts[tid] = cnt[tid]; }
}

// --------------------------------- weight transpose + fp32->bf16 ([K][N]->[N][K])
__global__ void k_convT(const float* __restrict__ src, __bf16* __restrict__ dst,
                        int K, int N)
{
  const int e = blockIdx.z;
  src += (size_t)e * K * N;
  unsigned short* d = reinterpret_cast<unsigned short*>(dst) + (size_t)e * K * N;
  const int n0 = blockIdx.x * 64, k0 = blockIdx.y * 64;
  __shared__ float tb[64][65];
  const int tid = threadIdx.x;
  const int r = tid >> 4, c = (tid & 15) * 4;
  #pragma unroll
  for (int rr = r; rr < 64; rr += 16) {
    float4 v = *reinterpret_cast<const float4*>(&src[(size_t)(k0+rr)*N + n0 + c]);
    tb[rr][c] = v.x; tb[rr][c+1] = v.y; tb[rr][c+2] = v.z; tb[rr][c+3] = v.w;
  }
  __syncthreads();
  #pragma unroll
  for (int rr = r; rr < 64; rr += 16) {
    ushort4 o;
    o.x = f2bf(tb[c+0][rr]); o.y = f2bf(tb[c+1][rr]);
    o.z = f2bf(tb[c+2][rr]); o.w = f2bf(tb[c+3][rr]);
    *reinterpret_cast<ushort4*>(&d[(size_t)(n0+rr)*K + k0 + c]) = o;
  }
}

// ------------------------------------------------------------- tiled bf16 GEMM
// 128x128 tile, BK=32, 4 waves (2x2), 16x16x32 MFMA, global_load_lds staging.
// PHASE2=false: hid[slot][NDIM] = gelu(A*Wt + b1)   (bf16)
// PHASE2=true : out[tok][C] += gate * (A*Wt + b2)   (fp32 atomic)
template<int KDIM, int NDIM, bool ROUTED, bool PHASE2>
__global__ __launch_bounds__(256)
void k_gemm(const __bf16* __restrict__ Abase, const __bf16* __restrict__ Wt,
            const float* __restrict__ bias, __bf16* __restrict__ hid,
            float* __restrict__ out,
            const int* __restrict__ listTok, const float* __restrict__ listGate,
            const int* __restrict__ offs, const int* __restrict__ cnts)
{
  const int e = blockIdx.z;
  int M, slotbase;
  if (ROUTED) { M = cnts[e]; slotbase = offs[e]; }
  else        { M = NTOK;    slotbase = e * NTOK; }
  const int m0 = blockIdx.y * 128;
  if (m0 >= M) return;
  const int n0 = blockIdx.x * 128;
  const int tid = threadIdx.x;

  __shared__ __align__(16) __bf16 Al[128 * 32];
  __shared__ __align__(16) __bf16 Bl[128 * 32];

  // staging: lane covers tile row sr (+64 for second instr), 8 elems at col sc
  const int sr = tid >> 2;
  const int sc = (tid & 3) * 8;
  int r0 = m0 + sr;       if (r0 > M - 1) r0 = M - 1;
  int r1 = m0 + 64 + sr;  if (r1 > M - 1) r1 = M - 1;
  size_t arow0, arow1;
  if (PHASE2)      { arow0 = (size_t)(slotbase + r0); arow1 = (size_t)(slotbase + r1); }
  else if (ROUTED) { arow0 = (size_t)listTok[slotbase + r0]; arow1 = (size_t)listTok[slotbase + r1]; }
  else             { arow0 = (size_t)r0; arow1 = (size_t)r1; }
  const __bf16* ga0 = Abase + arow0 * KDIM + sc;
  const __bf16* ga1 = Abase + arow1 * KDIM + sc;
  const __bf16* gb0 = Wt + ((size_t)e * NDIM + n0 + sr) * KDIM + sc;
  const __bf16* gb1 = gb0 + (size_t)64 * KDIM;

  char* AlB = (char*)Al;
  char* BlB = (char*)Bl;
  const unsigned wofs = (tid >> 6) * 1024;   // wave-uniform byte offset

  f32x4 acc[4][4];
  #pragma unroll
  for (int m = 0; m < 4; ++m)
    #pragma unroll
    for (int n = 0; n < 4; ++n) acc[m][n] = (f32x4){0.f, 0.f, 0.f, 0.f};

  const int w = tid >> 6, l = tid & 63;
  const int wr = (w >> 1) * 64, wc = (w & 1) * 64;
  const int lrow = l & 15;
  const int kq = (l >> 4) * 8;

  for (int k0 = 0; k0 < KDIM; k0 += 32) {
    async_ld16(AlB + wofs,        ga0 + k0);
    async_ld16(AlB + 4096 + wofs, ga1 + k0);
    async_ld16(BlB + wofs,        gb0 + k0);
    async_ld16(BlB + 4096 + wofs, gb1 + k0);
    __syncthreads();
    bf16x8 af[4], bfr[4];
    #pragma unroll
    for (int m = 0; m < 4; ++m)
      af[m] = *reinterpret_cast<const bf16x8*>(&Al[(wr + m*16 + lrow)*32 + kq]);
    #pragma unroll
    for (int n = 0; n < 4; ++n)
      bfr[n] = *reinterpret_cast<const bf16x8*>(&Bl[(wc + n*16 + lrow)*32 + kq]);
    #pragma unroll
    for (int m = 0; m < 4; ++m)
      #pragma unroll
      for (int n = 0; n < 4; ++n)
        acc[m][n] = mfma16(af[m], bfr[n], acc[m][n]);
    __syncthreads();
  }

  // epilogue — C/D layout: col = lane&15, row = (lane>>4)*4 + reg
  #pragma unroll
  for (int m = 0; m < 4; ++m) {
    const int rbase = m0 + wr + m*16 + (l >> 4) * 4;
    #pragma unroll
    for (int rg = 0; rg < 4; ++rg) {
      const int r = rbase + rg;
      if (r < M) {
        if (!PHASE2) {
          #pragma unroll
          for (int n = 0; n < 4; ++n) {
            const int col = n0 + wc + n*16 + lrow;
            float v = acc[m][n][rg] + bias[e * NDIM + col];
            v = 0.5f * v * (1.0f + erff(v * 0.70710678118654752f));   // exact GELU
            reinterpret_cast<unsigned short*>(hid)[(size_t)(slotbase + r) * NDIM + col] = f2bf(v);
          }
        } else {
          int tok; float g;
          if (ROUTED) { tok = listTok[slotbase + r]; g = listGate[slotbase + r]; }
          else        { tok = r; g = 1.0f; }
          #pragma unroll
          for (int n = 0; n < 4; ++n) {
            const int col = n0 + wc + n*16 + lrow;
            float v = acc[m][n][rg] + bias[e * NDIM + col];
            unsafeAtomicAdd(&out[(size_t)tok * C_ + col], g * v);
          }
        }
      }
    }
  }
}

// -----------------------------------------------------------------------------
extern "C" void kernel_launch(void* const* d_in, const int* in_sizes, int n_in,
                              void* d_out, int out_size, void* d_ws, size_t ws_size,
                              hipStream_t stream)
{
  const float* u    = (const float*)d_in[0];
  const float* gs   = (const float*)d_in[1];
  const float* W1s  = (const float*)d_in[2];
  const float* b1s  = (const float*)d_in[3];
  const float* W2s  = (const float*)d_in[4];
  const float* b2s  = (const float*)d_in[5];
  const float* gr   = (const float*)d_in[6];
  const float* W1r  = (const float*)d_in[7];
  const float* b1r  = (const float*)d_in[8];
  const float* W2r  = (const float*)d_in[9];
  const float* b2r  = (const float*)d_in[10];
  const float* cent = (const float*)d_in[11];
  float* out = (float*)d_out;

  char* ws = (char*)d_ws;
  size_t off = 0;
  auto alloc = [&](size_t bytes) -> char* {
    char* p = ws + off;
    off += (bytes + 255) & ~(size_t)255;
    return p;
  };
  __bf16* wbuf = (__bf16*)alloc((size_t)(ES_ + ER_) * H_ * C_ * 2);  // 84 MB (W1t, then reused for W2t)
  __bf16* xns  = (__bf16*)alloc((size_t)NTOK * C_ * 2);
  __bf16* xnr  = (__bf16*)alloc((size_t)NTOK * C_ * 2);
  __bf16* hids = (__bf16*)alloc((size_t)ES_ * NTOK * H_ * 2);        // 33.6 MB
  __bf16* hidr = (__bf16*)alloc((size_t)NTOK * 2 * H_ * 2);          // 33.6 MB (4096 slots)
  int*    tki      = (int*)  alloc(NTOK * 2 * 4);
  float*  tkg      = (float*)alloc(NTOK * 2 * 4);
  int*    listTok  = (int*)  alloc(NTOK * 2 * 4);
  float*  listGate = (float*)alloc(NTOK * 2 * 4);
  int*    offs     = (int*)  alloc(64);
  int*    cnts     = (int*)  alloc(64);
  if (off > ws_size) {
    fprintf(stderr, "ATHENA: WORKSPACE TOO SMALL: need %zu bytes, have %zu\n", off, ws_size);
    return;
  }

  __bf16* wt_s = wbuf;                       // experts 0..ES_-1
  __bf16* wt_r = wbuf + (size_t)ES_ * H_ * C_;

  k_init<<<dim3(NTOK * C_ / 1024), dim3(256), 0, stream>>>(u, out);
  k_prep<<<dim3(NTOK), dim3(256), 0, stream>>>(u, gs, gr, cent, xns, xnr, tki, tkg);
  k_build<<<dim3(1), dim3(256), 0, stream>>>(tki, tkg, listTok, listGate, offs, cnts);

  // W1 [E][C][H] -> bf16 [E][H][C]
  k_convT<<<dim3(H_/64, C_/64, ES_), dim3(256), 0, stream>>>(W1s, wt_s, C_, H_);
  k_convT<<<dim3(H_/64, C_/64, ER_), dim3(256), 0, stream>>>(W1r, wt_r, C_, H_);

  k_gemm<C_, H_, false, false><<<dim3(H_/128, NTOK/128, ES_), dim3(256), 0, stream>>>(
      xns, wt_s, b1s, hids, nullptr, nullptr, nullptr, nullptr, nullptr);
  k_gemm<C_, H_, true, false><<<dim3(H_/128, NTOK/128, ER_), dim3(256), 0, stream>>>(
      xnr, wt_r, b1r, hidr, nullptr, listTok, listGate, offs, cnts);

  // W2 [E][H][C] -> bf16 [E][C][H]   (reuses wbuf; stream order makes this safe)
  k_convT<<<dim3(C_/64, H_/64, ES_), dim3(256), 0, stream>>>(W2s, wt_s, H_, C_);
  k_convT<<<dim3(C_/64, H_/64, ER_), dim3(256), 0, stream>>>(W2r, wt_r, H_, C_);

  k_gemm<H_, C_, false, true><<<dim3(C_/128, NTOK/128, ES_), dim3(256), 0, stream>>>(
      hids, wt_s, b2s, nullptr, out, nullptr, nullptr, nullptr, nullptr);
  k_gemm<H_, C_, true, true><<<dim3(C_/128, NTOK/128, ER_), dim3(256), 0, stream>>>(
      hidr, wt_r, b2r, nullptr, out, listTok, listGate, offs, cnts);
}